// Round 1
// baseline (362.031 us; speedup 1.0000x reference)
//
#include <hip/hip_runtime.h>
#include <cstddef>

// Problem constants (B, S, E, H, MAXLEN) = (2, 2048, 1024, 16, 2048)
constexpr int Sn = 2048;
constexpr int En = 1024;
constexpr int Bn = 2;
constexpr int Hn = 16;
constexpr int NCH = 32;          // S / 64 chunks for the scan
constexpr int CHUNK = 64;

// ---------------------------------------------------------------------------
// GEMM (NT): C[m,n] = sum_k A[m,k] * W[n,k] + bias[n]
// A: M x K row-major, W: N x K row-major (this computes A @ W.T).
// APPLY_MASK: zero the whole output row when mask[row]==0 (masked v).
// Tile 64x64, BK=16, 256 threads, 4x4 micro-tile per thread.
// LDS stride 68 so &As[kk][ty*4] is 16B-aligned for ds_read_b128;
// lane->bank aliasing is <=2-way (free on gfx950, G4/m136).
// ---------------------------------------------------------------------------
template<bool APPLY_MASK>
__global__ __launch_bounds__(256)
void gemm_nt(const float* __restrict__ A, const float* __restrict__ W,
             const float* __restrict__ bias, const int* __restrict__ mask,
             float* __restrict__ C, int M, int N, int K)
{
    __shared__ float As[16][68];
    __shared__ float Ws[16][68];

    const int tid = threadIdx.x;
    const int bm  = blockIdx.y * 64;
    const int bn  = blockIdx.x * 64;
    const int lr  = tid >> 2;          // 0..63: row within tile for staging
    const int lk  = (tid & 3) << 2;    // 0,4,8,12: k offset (float4) for staging
    const int tx  = tid & 15;          // 0..15: output col group
    const int ty  = tid >> 4;          // 0..15: output row group

    float acc[4][4] = {};

    const float* Arow = A + (size_t)(bm + lr) * K + lk;
    const float* Wrow = W + (size_t)(bn + lr) * K + lk;

    for (int k0 = 0; k0 < K; k0 += 16) {
        const float4 av = *(const float4*)(Arow + k0);
        const float4 wv = *(const float4*)(Wrow + k0);
        __syncthreads();   // previous iteration's LDS reads done
        As[lk + 0][lr] = av.x; As[lk + 1][lr] = av.y;
        As[lk + 2][lr] = av.z; As[lk + 3][lr] = av.w;
        Ws[lk + 0][lr] = wv.x; Ws[lk + 1][lr] = wv.y;
        Ws[lk + 2][lr] = wv.z; Ws[lk + 3][lr] = wv.w;
        __syncthreads();
#pragma unroll
        for (int kk = 0; kk < 16; ++kk) {
            const float4 a = *(const float4*)&As[kk][ty * 4];
            const float4 w = *(const float4*)&Ws[kk][tx * 4];
            const float ar[4] = {a.x, a.y, a.z, a.w};
            const float wr[4] = {w.x, w.y, w.z, w.w};
#pragma unroll
            for (int i = 0; i < 4; ++i)
#pragma unroll
                for (int j = 0; j < 4; ++j)
                    acc[i][j] = fmaf(ar[i], wr[j], acc[i][j]);
        }
    }

#pragma unroll
    for (int i = 0; i < 4; ++i) {
        const int row = bm + ty * 4 + i;
        float mfac = 1.0f;
        if (APPLY_MASK) mfac = (mask[row] == 0) ? 0.0f : 1.0f;
#pragma unroll
        for (int j = 0; j < 4; ++j) {
            const int col = bn + tx * 4 + j;
            C[(size_t)row * N + col] = (acc[i][j] + bias[col]) * mfac;
        }
    }
}

// ---------------------------------------------------------------------------
// Pass 1 of scan: per-chunk sums of vm along s.
// grid: (E/256, NCH, B); 256 threads over e.
// ---------------------------------------------------------------------------
__global__ __launch_bounds__(256)
void chunk_sum(const float* __restrict__ vm, float* __restrict__ csum)
{
    const int e = blockIdx.x * 256 + threadIdx.x;
    const int c = blockIdx.y;
    const int b = blockIdx.z;
    const size_t base = ((size_t)b * Sn + c * CHUNK) * En + e;
    float s = 0.0f;
    for (int t = 0; t < CHUNK; ++t) s += vm[base + (size_t)t * En];
    csum[((size_t)b * NCH + c) * En + e] = s;
}

// ---------------------------------------------------------------------------
// Pass 2: exclusive scan over the NCH chunk sums per (b,e) column + total T.
// grid: B*E/256 blocks.
// ---------------------------------------------------------------------------
__global__ __launch_bounds__(256)
void chunk_scan(const float* __restrict__ csum, float* __restrict__ cscan,
                float* __restrict__ Tbuf)
{
    const int idx = blockIdx.x * 256 + threadIdx.x;   // b*E + e
    const int b = idx >> 10;   // / En
    const int e = idx & (En - 1);
    float run = 0.0f;
    for (int c = 0; c < NCH; ++c) {
        const size_t off = ((size_t)b * NCH + c) * En + e;
        const float v = csum[off];
        cscan[off] = run;
        run += v;
    }
    Tbuf[idx] = run;
}

// ---------------------------------------------------------------------------
// Pass 3: fused within-chunk prefix + weighted combine.
// out_pre[b,i,e] = (w2*Pref[i&~1] + (i odd)*w1*vm[i-1] + w0*(T - Pref[i])) / Z
// Z = (i&~1)*w2 + (i odd)*w1 + (S-i)*w0 + 1e-8   (pre-mask normalization)
// Chunks start even, so vm[i-1] for odd i is always the previous iteration.
// ---------------------------------------------------------------------------
__global__ __launch_bounds__(256)
void combine(const float* __restrict__ vm, const float* __restrict__ cscan,
             const float* __restrict__ Tbuf, const float* __restrict__ hier,
             float* __restrict__ opre)
{
    const int e = blockIdx.x * 256 + threadIdx.x;
    const int c = blockIdx.y;
    const int b = blockIdx.z;
    const int h = e >> 6;   // dh = 64

    const float w0 = hier[((size_t)b * Hn + h) * 3 + 0];
    const float w1 = hier[((size_t)b * Hn + h) * 3 + 1] * 0.5f;
    const float w2 = hier[((size_t)b * Hn + h) * 3 + 2] * 0.25f;
    const float T  = Tbuf[(size_t)b * En + e];

    float run  = cscan[((size_t)b * NCH + c) * En + e];  // Pref at chunk start
    float prev = 0.0f;
    const size_t base = ((size_t)b * Sn + c * CHUNK) * En + e;

    for (int t = 0; t < CHUNK; ++t) {
        const int i = c * CHUNK + t;
        const float cur = vm[base + (size_t)t * En];
        float num, Z;
        if (i & 1) {
            const float pm = run - prev;               // Pref[i-1]
            num = w2 * pm + w1 * prev + w0 * (T - run);
            Z = (float)(i - 1) * w2 + w1 + (float)(Sn - i) * w0 + 1e-8f;
        } else {
            num = w2 * run + w0 * (T - run);
            Z = (float)i * w2 + (float)(Sn - i) * w0 + 1e-8f;
        }
        opre[base + (size_t)t * En] = num / Z;
        run  += cur;
        prev  = cur;
    }
}

// ---------------------------------------------------------------------------
extern "C" void kernel_launch(void* const* d_in, const int* in_sizes, int n_in,
                              void* d_out, int out_size, void* d_ws, size_t ws_size,
                              hipStream_t stream)
{
    // setup_inputs order:
    // 0:x 1:attention_mask 2:level_indices 3:Wq 4:bq 5:Wk 6:bk 7:Wv 8:bv 9:hier 10:Wo 11:bo
    const float* x    = (const float*)d_in[0];
    const int*   mask = (const int*)d_in[1];
    // level_indices (d_in[2]) is replaced by its closed form; Wq/bq/Wk/bk are dead.
    const float* Wv   = (const float*)d_in[7];
    const float* bv   = (const float*)d_in[8];
    const float* hier = (const float*)d_in[9];
    const float* Wo   = (const float*)d_in[10];
    const float* bo   = (const float*)d_in[11];
    float* out = (float*)d_out;

    float* ws    = (float*)d_ws;
    float* vm    = ws;                                   // B*S*E
    float* csum  = vm   + (size_t)Bn * Sn * En;          // B*NCH*E
    float* cscan = csum + (size_t)Bn * NCH * En;         // B*NCH*E
    float* Tbuf  = cscan + (size_t)Bn * NCH * En;        // B*E
    float* opre  = Tbuf + (size_t)Bn * En;               // B*S*E

    const int M = Bn * Sn, N = En, K = En;
    dim3 threads(256);
    dim3 gemm_grid(N / 64, M / 64);

    // 1) vm = mask ? (x @ Wv.T + bv) : 0
    gemm_nt<true><<<gemm_grid, threads, 0, stream>>>(x, Wv, bv, mask, vm, M, N, K);
    // 2-3) two-level exclusive prefix scan of vm along s
    chunk_sum<<<dim3(En / 256, NCH, Bn), threads, 0, stream>>>(vm, csum);
    chunk_scan<<<dim3((Bn * En) / 256), threads, 0, stream>>>(csum, cscan, Tbuf);
    // 4) weighted combine -> out_pre
    combine<<<dim3(En / 256, NCH, Bn), threads, 0, stream>>>(vm, cscan, Tbuf, hier, opre);
    // 5) out = out_pre @ Wo.T + bo
    gemm_nt<false><<<gemm_grid, threads, 0, stream>>>(opre, Wo, bo, nullptr, out, M, N, K);
}

// Round 2
// 200.377 us; speedup vs baseline: 1.8067x; 1.8067x over previous
//
#include <hip/hip_runtime.h>
#include <cstdint>
#include <cstddef>

// Problem constants (B, S, E, H, MAXLEN) = (2, 2048, 1024, 16, 2048)
constexpr int Sn = 2048;
constexpr int En = 1024;
constexpr int Bn = 2;
constexpr int Hn = 16;
constexpr int NCH = 32;
constexpr int CHUNK = 64;

typedef __bf16 bf16x8 __attribute__((ext_vector_type(8)));
typedef float  f32x4  __attribute__((ext_vector_type(4)));

#define GLOBAL_AS(p) ((const __attribute__((address_space(1))) void*)(p))
#define LDS_AS(p)    ((__attribute__((address_space(3))) void*)(p))

__device__ __forceinline__ unsigned short f2bf(float f) {
    union { float f; uint32_t u; } v; v.f = f;
    const uint32_t u = v.u;
    return (unsigned short)((u + 0x7fffu + ((u >> 16) & 1u)) >> 16);  // RNE
}

// ---------------------------------------------------------------------------
// fp32 -> bf16 cast, 4 elements/thread. n must be divisible by 1024.
// ---------------------------------------------------------------------------
__global__ __launch_bounds__(256)
void cast_bf16(const float* __restrict__ src, unsigned short* __restrict__ dst, int n)
{
    const int i = (blockIdx.x * 256 + threadIdx.x) * 4;
    if (i >= n) return;
    const float4 v = *(const float4*)(src + i);
    ushort4 o;
    o.x = f2bf(v.x); o.y = f2bf(v.y); o.z = f2bf(v.z); o.w = f2bf(v.w);
    *(ushort4*)(dst + i) = o;
}

// ---------------------------------------------------------------------------
// bf16 MFMA GEMM (NT): C[m,n] = sum_k A[m,k]*W[n,k] + bias[n], fp32 out.
// m97 ladder structure: 128x128 tile, BK=32, 256 threads = 4 waves in 2x2,
// each wave a 64x64 sub-tile via 4x4 grid of 16x16x32 MFMAs.
// Staging: global_load_lds width=16 into MFMA-fragment-order LDS:
//   chunk j (1024 B) = rows [16j,16j+16) x k[0,32): lane l -> row 16j+(l&15),
//   k (l>>4)*8..+8. Compute reads a_frag at chunk_base + lane*16 B ->
//   lane-contiguous ds_read_b128, conflict-free.
// APPLY_MASK: zero whole output row when mask[row]==0.
// ---------------------------------------------------------------------------
template<bool APPLY_MASK>
__global__ __launch_bounds__(256)
void gemm_mfma(const unsigned short* __restrict__ A, const unsigned short* __restrict__ Bw,
               const float* __restrict__ bias, const int* __restrict__ mask,
               float* __restrict__ C, int M, int N, int K)
{
    __shared__ __align__(16) unsigned short As[128 * 32];
    __shared__ __align__(16) unsigned short Bs[128 * 32];

    const int tid  = threadIdx.x;
    const int lane = tid & 63;
    const int wv   = tid >> 6;      // wave 0..3
    const int wr   = wv >> 1;       // wave row (0..1)
    const int wc   = wv & 1;        // wave col (0..1)
    const int bm   = blockIdx.y * 128;
    const int bn   = blockIdx.x * 128;
    const int m16  = lane & 15;
    const int kq   = lane >> 4;     // 0..3: k-quarter (staging) / row-quad (C/D)

    f32x4 acc[4][4] = {};

    // Wave wv stages chunks {2wv, 2wv+1} of both A and B.
    const int j0 = 2 * wv, j1 = 2 * wv + 1;
    const unsigned short* gA0 = A  + (size_t)(bm + 16 * j0 + m16) * K + kq * 8;
    const unsigned short* gA1 = A  + (size_t)(bm + 16 * j1 + m16) * K + kq * 8;
    const unsigned short* gB0 = Bw + (size_t)(bn + 16 * j0 + m16) * K + kq * 8;
    const unsigned short* gB1 = Bw + (size_t)(bn + 16 * j1 + m16) * K + kq * 8;
    unsigned short* lA0 = &As[j0 * 512];   // wave-uniform LDS bases
    unsigned short* lA1 = &As[j1 * 512];
    unsigned short* lB0 = &Bs[j0 * 512];
    unsigned short* lB1 = &Bs[j1 * 512];

    for (int k0 = 0; k0 < K; k0 += 32) {
        __syncthreads();   // previous iteration's frag reads done
        __builtin_amdgcn_global_load_lds(GLOBAL_AS(gA0 + k0), LDS_AS(lA0), 16, 0, 0);
        __builtin_amdgcn_global_load_lds(GLOBAL_AS(gA1 + k0), LDS_AS(lA1), 16, 0, 0);
        __builtin_amdgcn_global_load_lds(GLOBAL_AS(gB0 + k0), LDS_AS(lB0), 16, 0, 0);
        __builtin_amdgcn_global_load_lds(GLOBAL_AS(gB1 + k0), LDS_AS(lB1), 16, 0, 0);
        __syncthreads();   // implies vmcnt(0): staging landed

        bf16x8 af[4], bfr[4];
#pragma unroll
        for (int i = 0; i < 4; ++i)
            af[i] = *(const bf16x8*)&As[(wr * 4 + i) * 512 + lane * 8];
#pragma unroll
        for (int j = 0; j < 4; ++j)
            bfr[j] = *(const bf16x8*)&Bs[(wc * 4 + j) * 512 + lane * 8];
#pragma unroll
        for (int i = 0; i < 4; ++i)
#pragma unroll
            for (int j = 0; j < 4; ++j)
                acc[i][j] = __builtin_amdgcn_mfma_f32_16x16x32_bf16(af[i], bfr[j], acc[i][j], 0, 0, 0);
    }

    // Epilogue. C/D layout: col = lane&15, row = (lane>>4)*4 + reg.
#pragma unroll
    for (int i = 0; i < 4; ++i) {
        const int r0 = bm + wr * 64 + i * 16 + kq * 4;
#pragma unroll
        for (int j = 0; j < 4; ++j) {
            const int c0 = bn + wc * 64 + j * 16 + m16;
            const float bcol = bias[c0];
#pragma unroll
            for (int r = 0; r < 4; ++r) {
                const int row = r0 + r;
                float val = acc[i][j][r] + bcol;
                if (APPLY_MASK) val = (mask[row] == 0) ? 0.0f : val;
                C[(size_t)row * N + c0] = val;
            }
        }
    }
}

// ---------------------------------------------------------------------------
// Pass 1 of scan: per-chunk sums of vm along s.
// ---------------------------------------------------------------------------
__global__ __launch_bounds__(256)
void chunk_sum(const float* __restrict__ vm, float* __restrict__ csum)
{
    const int e = blockIdx.x * 256 + threadIdx.x;
    const int c = blockIdx.y;
    const int b = blockIdx.z;
    const size_t base = ((size_t)b * Sn + c * CHUNK) * En + e;
    float s = 0.0f;
    for (int t = 0; t < CHUNK; ++t) s += vm[base + (size_t)t * En];
    csum[((size_t)b * NCH + c) * En + e] = s;
}

// ---------------------------------------------------------------------------
// Pass 2: exclusive scan over chunk sums per (b,e) + total T.
// ---------------------------------------------------------------------------
__global__ __launch_bounds__(256)
void chunk_scan(const float* __restrict__ csum, float* __restrict__ cscan,
                float* __restrict__ Tbuf)
{
    const int idx = blockIdx.x * 256 + threadIdx.x;   // b*E + e
    const int b = idx >> 10;
    const int e = idx & (En - 1);
    float run = 0.0f;
    for (int c = 0; c < NCH; ++c) {
        const size_t off = ((size_t)b * NCH + c) * En + e;
        const float v = csum[off];
        cscan[off] = run;
        run += v;
    }
    Tbuf[idx] = run;
}

// ---------------------------------------------------------------------------
// Pass 3: fused within-chunk prefix + weighted combine -> opre in BF16.
// out_pre[b,i,e] = (w2*Pref[i&~1] + (i odd)*w1*vm[i-1] + w0*(T - Pref[i])) / Z
// Z = (i&~1)*w2 + (i odd)*w1 + (S-i)*w0 + 1e-8   (pre-mask normalization)
// ---------------------------------------------------------------------------
__global__ __launch_bounds__(256)
void combine(const float* __restrict__ vm, const float* __restrict__ cscan,
             const float* __restrict__ Tbuf, const float* __restrict__ hier,
             unsigned short* __restrict__ opre)
{
    const int e = blockIdx.x * 256 + threadIdx.x;
    const int c = blockIdx.y;
    const int b = blockIdx.z;
    const int h = e >> 6;   // dh = 64

    const float w0 = hier[((size_t)b * Hn + h) * 3 + 0];
    const float w1 = hier[((size_t)b * Hn + h) * 3 + 1] * 0.5f;
    const float w2 = hier[((size_t)b * Hn + h) * 3 + 2] * 0.25f;
    const float T  = Tbuf[(size_t)b * En + e];

    float run  = cscan[((size_t)b * NCH + c) * En + e];
    float prev = 0.0f;
    const size_t base = ((size_t)b * Sn + c * CHUNK) * En + e;

    for (int t = 0; t < CHUNK; ++t) {
        const int i = c * CHUNK + t;
        const float cur = vm[base + (size_t)t * En];
        float num, Z;
        if (i & 1) {
            const float pm = run - prev;               // Pref[i-1]
            num = w2 * pm + w1 * prev + w0 * (T - run);
            Z = (float)(i - 1) * w2 + w1 + (float)(Sn - i) * w0 + 1e-8f;
        } else {
            num = w2 * run + w0 * (T - run);
            Z = (float)i * w2 + (float)(Sn - i) * w0 + 1e-8f;
        }
        opre[base + (size_t)t * En] = f2bf(num / Z);
        run  += cur;
        prev  = cur;
    }
}

// ---------------------------------------------------------------------------
extern "C" void kernel_launch(void* const* d_in, const int* in_sizes, int n_in,
                              void* d_out, int out_size, void* d_ws, size_t ws_size,
                              hipStream_t stream)
{
    // 0:x 1:attention_mask 2:level_indices 3:Wq 4:bq 5:Wk 6:bk 7:Wv 8:bv 9:hier 10:Wo 11:bo
    const float* x    = (const float*)d_in[0];
    const int*   mask = (const int*)d_in[1];
    const float* Wv   = (const float*)d_in[7];
    const float* bv   = (const float*)d_in[8];
    const float* hier = (const float*)d_in[9];
    const float* Wo   = (const float*)d_in[10];
    const float* bo   = (const float*)d_in[11];
    float* out = (float*)d_out;

    const int M = Bn * Sn, N = En, K = En;

    char* ws = (char*)d_ws;
    unsigned short* xb    = (unsigned short*)ws;                ws += (size_t)M * K * 2;       // 8 MB
    unsigned short* Wvb   = (unsigned short*)ws;                ws += (size_t)N * K * 2;       // 2 MB
    unsigned short* Wob   = (unsigned short*)ws;                ws += (size_t)N * K * 2;       // 2 MB
    float*          vm    = (float*)ws;                         ws += (size_t)M * N * 4;       // 16 MB
    float*          csum  = (float*)ws;                         ws += (size_t)Bn * NCH * En * 4;
    float*          cscan = (float*)ws;                         ws += (size_t)Bn * NCH * En * 4;
    float*          Tbuf  = (float*)ws;                         ws += (size_t)Bn * En * 4;
    unsigned short* opreb = (unsigned short*)ws;                ws += (size_t)M * N * 2;       // 8 MB

    dim3 threads(256);

    // Casts to bf16
    cast_bf16<<<dim3((M * K) / 1024), threads, 0, stream>>>(x,  xb,  M * K);
    cast_bf16<<<dim3((N * K) / 1024), threads, 0, stream>>>(Wv, Wvb, N * K);
    cast_bf16<<<dim3((N * K) / 1024), threads, 0, stream>>>(Wo, Wob, N * K);

    dim3 gemm_grid(N / 128, M / 128);   // (8, 32)

    // 1) vm = mask ? (x @ Wv.T + bv) : 0   (fp32 out for the scan)
    gemm_mfma<true><<<gemm_grid, threads, 0, stream>>>(xb, Wvb, bv, mask, vm, M, N, K);
    // 2-3) two-level exclusive prefix scan of vm along s
    chunk_sum<<<dim3(En / 256, NCH, Bn), threads, 0, stream>>>(vm, csum);
    chunk_scan<<<dim3((Bn * En) / 256), threads, 0, stream>>>(csum, cscan, Tbuf);
    // 4) weighted combine -> opre (bf16)
    combine<<<dim3(En / 256, NCH, Bn), threads, 0, stream>>>(vm, cscan, Tbuf, hier, opreb);
    // 5) out = opre @ Wo.T + bo
    gemm_mfma<false><<<gemm_grid, threads, 0, stream>>>(opreb, Wob, bo, nullptr, out, M, N, K);
}

// Round 3
// 177.766 us; speedup vs baseline: 2.0366x; 1.1272x over previous
//
#include <hip/hip_runtime.h>
#include <cstdint>
#include <cstddef>

// Problem constants (B, S, E, H, MAXLEN) = (2, 2048, 1024, 16, 2048)
constexpr int Sn = 2048;
constexpr int En = 1024;
constexpr int Bn = 2;
constexpr int Hn = 16;
constexpr int NCH = 32;
constexpr int CHUNK = 64;

typedef __bf16 bf16x8 __attribute__((ext_vector_type(8)));
typedef float  f32x4  __attribute__((ext_vector_type(4)));

#define GLOBAL_AS(p) ((const __attribute__((address_space(1))) void*)(p))
#define LDS_AS(p)    ((__attribute__((address_space(3))) void*)(p))

__device__ __forceinline__ unsigned short f2bf(float f) {
    union { float f; uint32_t u; } v; v.f = f;
    const uint32_t u = v.u;
    return (unsigned short)((u + 0x7fffu + ((u >> 16) & 1u)) >> 16);  // RNE
}
__device__ __forceinline__ float bf2f_lo(uint32_t u) {
    union { uint32_t u; float f; } v; v.u = u << 16; return v.f;
}
__device__ __forceinline__ float bf2f_hi(uint32_t u) {
    union { uint32_t u; float f; } v; v.u = u & 0xffff0000u; return v.f;
}

// ---------------------------------------------------------------------------
// Fused fp32 -> bf16 cast of x (XN), Wv (WN), Wo (WN) in one launch.
// ---------------------------------------------------------------------------
constexpr int XN = Bn * Sn * En;   // 4194304
constexpr int WN = En * En;        // 1048576

__global__ __launch_bounds__(256)
void cast3(const float* __restrict__ x, const float* __restrict__ Wv,
           const float* __restrict__ Wo, unsigned short* __restrict__ xb,
           unsigned short* __restrict__ Wvb, unsigned short* __restrict__ Wob)
{
    const int i = (blockIdx.x * 256 + threadIdx.x) * 4;
    const float* src; unsigned short* dst; int off;
    if (i < XN)           { src = x;  dst = xb;  off = i; }
    else if (i < XN + WN) { src = Wv; dst = Wvb; off = i - XN; }
    else                  { src = Wo; dst = Wob; off = i - XN - WN; }
    const float4 v = *(const float4*)(src + off);
    ushort4 o;
    o.x = f2bf(v.x); o.y = f2bf(v.y); o.z = f2bf(v.z); o.w = f2bf(v.w);
    *(ushort4*)(dst + off) = o;
}

// ---------------------------------------------------------------------------
// bf16 MFMA GEMM (NT): C[m,n] = sum_k A[m,k]*W[n,k] + bias[n].
// Tile 128(M) x 64(N), BK=32, 256 threads = 4 waves in 2x2 over (128,64):
// wave tile 64x32 = 4x2 grid of 16x16x32 MFMAs. Grid = (N/64, M/128) =
// (16, 32) = 512 blocks -> 2 blocks/CU co-resident so one block's MFMAs
// overlap the other's barrier drain (m114).
// Staging: global_load_lds width=16 into MFMA-fragment-order LDS
// (chunk = 16 rows x 32 k = 1024 B, lane l -> row 16j+(l&15), k (l>>4)*8).
// Compute reads fragments at chunk_base + lane*16 B (conflict-free b128).
// APPLY_MASK zeroes output rows with mask==0; OUT_BF16 stores bf16.
// ---------------------------------------------------------------------------
template<bool APPLY_MASK, bool OUT_BF16>
__global__ __launch_bounds__(256)
void gemm_mfma(const unsigned short* __restrict__ A, const unsigned short* __restrict__ Bw,
               const float* __restrict__ bias, const int* __restrict__ mask,
               void* __restrict__ Cv, int M, int N, int K)
{
    __shared__ __align__(16) unsigned short As[128 * 32];  // 8 KB
    __shared__ __align__(16) unsigned short Bs[64 * 32];   // 4 KB

    const int tid  = threadIdx.x;
    const int lane = tid & 63;
    const int wv   = tid >> 6;      // wave 0..3
    const int wr   = wv >> 1;       // wave row (0..1) -> M
    const int wc   = wv & 1;        // wave col (0..1) -> N
    const int bm   = blockIdx.y * 128;
    const int bn   = blockIdx.x * 64;
    const int m16  = lane & 15;
    const int kq   = lane >> 4;     // k-quarter (staging) / row-quad (C/D)

    f32x4 acc[4][2] = {};

    // Wave wv stages A-chunks {2wv, 2wv+1} and B-chunk {wv}.
    const int j0 = 2 * wv, j1 = 2 * wv + 1;
    const unsigned short* gA0 = A  + (size_t)(bm + 16 * j0 + m16) * K + kq * 8;
    const unsigned short* gA1 = A  + (size_t)(bm + 16 * j1 + m16) * K + kq * 8;
    const unsigned short* gB0 = Bw + (size_t)(bn + 16 * wv + m16) * K + kq * 8;
    unsigned short* lA0 = &As[j0 * 512];   // wave-uniform LDS bases
    unsigned short* lA1 = &As[j1 * 512];
    unsigned short* lB0 = &Bs[wv * 512];

    for (int k0 = 0; k0 < K; k0 += 32) {
        __syncthreads();   // previous iteration's frag reads done
        __builtin_amdgcn_global_load_lds(GLOBAL_AS(gA0 + k0), LDS_AS(lA0), 16, 0, 0);
        __builtin_amdgcn_global_load_lds(GLOBAL_AS(gA1 + k0), LDS_AS(lA1), 16, 0, 0);
        __builtin_amdgcn_global_load_lds(GLOBAL_AS(gB0 + k0), LDS_AS(lB0), 16, 0, 0);
        __syncthreads();   // implies vmcnt(0): staging landed

        bf16x8 af[4], bfr[2];
#pragma unroll
        for (int i = 0; i < 4; ++i)
            af[i] = *(const bf16x8*)&As[(wr * 4 + i) * 512 + lane * 8];
#pragma unroll
        for (int j = 0; j < 2; ++j)
            bfr[j] = *(const bf16x8*)&Bs[(wc * 2 + j) * 512 + lane * 8];
#pragma unroll
        for (int i = 0; i < 4; ++i)
#pragma unroll
            for (int j = 0; j < 2; ++j)
                acc[i][j] = __builtin_amdgcn_mfma_f32_16x16x32_bf16(af[i], bfr[j], acc[i][j], 0, 0, 0);
    }

    // Epilogue. C/D layout: col = lane&15, row = (lane>>4)*4 + reg.
#pragma unroll
    for (int i = 0; i < 4; ++i) {
        const int r0 = bm + wr * 64 + i * 16 + kq * 4;
#pragma unroll
        for (int j = 0; j < 2; ++j) {
            const int c0 = bn + wc * 32 + j * 16 + m16;
            const float bcol = bias[c0];
#pragma unroll
            for (int r = 0; r < 4; ++r) {
                const int row = r0 + r;
                float val = acc[i][j][r] + bcol;
                if (APPLY_MASK) val = (mask[row] == 0) ? 0.0f : val;
                if (OUT_BF16)
                    ((unsigned short*)Cv)[(size_t)row * N + c0] = f2bf(val);
                else
                    ((float*)Cv)[(size_t)row * N + c0] = val;
            }
        }
    }
}

// ---------------------------------------------------------------------------
// Pass 1 of scan: per-chunk sums of vm (bf16) along s. 2 columns/thread.
// grid: (E/512, NCH, B).
// ---------------------------------------------------------------------------
__global__ __launch_bounds__(256)
void chunk_sum(const unsigned short* __restrict__ vm, float* __restrict__ csum)
{
    const int ep = blockIdx.x * 256 + threadIdx.x;   // column pair
    const int e = ep * 2;
    const int c = blockIdx.y;
    const int b = blockIdx.z;
    const size_t base = ((size_t)b * Sn + c * CHUNK) * En + e;
    float s0 = 0.0f, s1 = 0.0f;
    for (int t = 0; t < CHUNK; ++t) {
        const uint32_t u = *(const uint32_t*)(vm + base + (size_t)t * En);
        s0 += bf2f_lo(u);
        s1 += bf2f_hi(u);
    }
    const size_t o = ((size_t)b * NCH + c) * En + e;
    csum[o] = s0;
    csum[o + 1] = s1;
}

// ---------------------------------------------------------------------------
// Pass 2: exclusive scan over chunk sums per (b,e) + total T.
// ---------------------------------------------------------------------------
__global__ __launch_bounds__(256)
void chunk_scan(const float* __restrict__ csum, float* __restrict__ cscan,
                float* __restrict__ Tbuf)
{
    const int idx = blockIdx.x * 256 + threadIdx.x;   // b*E + e
    const int b = idx >> 10;
    const int e = idx & (En - 1);
    float run = 0.0f;
    for (int c = 0; c < NCH; ++c) {
        const size_t off = ((size_t)b * NCH + c) * En + e;
        const float v = csum[off];
        cscan[off] = run;
        run += v;
    }
    Tbuf[idx] = run;
}

// ---------------------------------------------------------------------------
// Pass 3: fused within-chunk prefix + weighted combine -> opre (bf16).
// out_pre[b,i,e] = (w2*Pref[i&~1] + (i odd)*w1*vm[i-1] + w0*(T - Pref[i])) / Z
// Z = (i&~1)*w2 + (i odd)*w1 + (S-i)*w0 + 1e-8   (pre-mask normalization)
// 2 columns/thread (same head since e is even and dh=64).
// ---------------------------------------------------------------------------
__global__ __launch_bounds__(256)
void combine(const unsigned short* __restrict__ vm, const float* __restrict__ cscan,
             const float* __restrict__ Tbuf, const float* __restrict__ hier,
             unsigned short* __restrict__ opre)
{
    const int ep = blockIdx.x * 256 + threadIdx.x;
    const int e = ep * 2;
    const int c = blockIdx.y;
    const int b = blockIdx.z;
    const int h = e >> 6;   // dh = 64

    const float w0 = hier[((size_t)b * Hn + h) * 3 + 0];
    const float w1 = hier[((size_t)b * Hn + h) * 3 + 1] * 0.5f;
    const float w2 = hier[((size_t)b * Hn + h) * 3 + 2] * 0.25f;
    const float T0 = Tbuf[(size_t)b * En + e];
    const float T1 = Tbuf[(size_t)b * En + e + 1];

    const size_t co = ((size_t)b * NCH + c) * En + e;
    float run0 = cscan[co], run1 = cscan[co + 1];
    float prev0 = 0.0f, prev1 = 0.0f;
    const size_t base = ((size_t)b * Sn + c * CHUNK) * En + e;

    for (int t = 0; t < CHUNK; ++t) {
        const int i = c * CHUNK + t;
        const uint32_t u = *(const uint32_t*)(vm + base + (size_t)t * En);
        const float cur0 = bf2f_lo(u), cur1 = bf2f_hi(u);
        float num0, num1, Z;
        if (i & 1) {
            num0 = w2 * (run0 - prev0) + w1 * prev0 + w0 * (T0 - run0);
            num1 = w2 * (run1 - prev1) + w1 * prev1 + w0 * (T1 - run1);
            Z = (float)(i - 1) * w2 + w1 + (float)(Sn - i) * w0 + 1e-8f;
        } else {
            num0 = w2 * run0 + w0 * (T0 - run0);
            num1 = w2 * run1 + w0 * (T1 - run1);
            Z = (float)i * w2 + (float)(Sn - i) * w0 + 1e-8f;
        }
        const float rz = 1.0f / Z;
        const uint32_t o = (uint32_t)f2bf(num0 * rz) | ((uint32_t)f2bf(num1 * rz) << 16);
        *(uint32_t*)(opre + base + (size_t)t * En) = o;
        run0 += cur0; run1 += cur1;
        prev0 = cur0; prev1 = cur1;
    }
}

// ---------------------------------------------------------------------------
extern "C" void kernel_launch(void* const* d_in, const int* in_sizes, int n_in,
                              void* d_out, int out_size, void* d_ws, size_t ws_size,
                              hipStream_t stream)
{
    // 0:x 1:attention_mask 2:level_indices 3:Wq 4:bq 5:Wk 6:bk 7:Wv 8:bv 9:hier 10:Wo 11:bo
    const float* x    = (const float*)d_in[0];
    const int*   mask = (const int*)d_in[1];
    const float* Wv   = (const float*)d_in[7];
    const float* bv   = (const float*)d_in[8];
    const float* hier = (const float*)d_in[9];
    const float* Wo   = (const float*)d_in[10];
    const float* bo   = (const float*)d_in[11];
    float* out = (float*)d_out;

    const int M = Bn * Sn, N = En, K = En;

    char* ws = (char*)d_ws;
    unsigned short* xb    = (unsigned short*)ws;  ws += (size_t)M * K * 2;        // 8 MB
    unsigned short* Wvb   = (unsigned short*)ws;  ws += (size_t)N * K * 2;        // 2 MB
    unsigned short* Wob   = (unsigned short*)ws;  ws += (size_t)N * K * 2;        // 2 MB
    unsigned short* vmb   = (unsigned short*)ws;  ws += (size_t)M * N * 2;        // 8 MB
    float*          csum  = (float*)ws;           ws += (size_t)Bn * NCH * En * 4;
    float*          cscan = (float*)ws;           ws += (size_t)Bn * NCH * En * 4;
    float*          Tbuf  = (float*)ws;           ws += (size_t)Bn * En * 4;
    unsigned short* opreb = (unsigned short*)ws;  ws += (size_t)M * N * 2;        // 8 MB

    dim3 threads(256);

    // Fused casts to bf16 (x, Wv, Wo)
    cast3<<<dim3((XN + 2 * WN) / 1024), threads, 0, stream>>>(x, Wv, Wo, xb, Wvb, Wob);

    dim3 gemm_grid(N / 64, M / 128);   // (16, 32) = 512 blocks = 2/CU

    // 1) vm = mask ? (x @ Wv.T + bv) : 0   (bf16 out for the scan)
    gemm_mfma<true, true><<<gemm_grid, threads, 0, stream>>>(xb, Wvb, bv, mask, vmb, M, N, K);
    // 2-3) two-level exclusive prefix scan of vm along s
    chunk_sum<<<dim3(En / 512, NCH, Bn), threads, 0, stream>>>(vmb, csum);
    chunk_scan<<<dim3((Bn * En) / 256), threads, 0, stream>>>(csum, cscan, Tbuf);
    // 4) weighted combine -> opre (bf16)
    combine<<<dim3(En / 512, NCH, Bn), threads, 0, stream>>>(vmb, cscan, Tbuf, hier, opreb);
    // 5) out = opre @ Wo.T + bo  (fp32 out)
    gemm_mfma<false, false><<<gemm_grid, threads, 0, stream>>>(opreb, Wob, bo, nullptr, out, M, N, K);
}

// Round 4
// 172.277 us; speedup vs baseline: 2.1015x; 1.0319x over previous
//
#include <hip/hip_runtime.h>
#include <cstdint>
#include <cstddef>

// Problem constants (B, S, E, H, MAXLEN) = (2, 2048, 1024, 16, 2048)
constexpr int Sn = 2048;
constexpr int En = 1024;
constexpr int Bn = 2;
constexpr int Hn = 16;
constexpr int NCH = 32;          // chunks per batch (S/CHUNK)
constexpr int CHUNK = 64;

typedef __bf16 bf16x8 __attribute__((ext_vector_type(8)));
typedef float  f32x4  __attribute__((ext_vector_type(4)));

#define GLOBAL_AS(p) ((const __attribute__((address_space(1))) void*)(p))
#define LDS_AS(p)    ((__attribute__((address_space(3))) void*)(p))

__device__ __forceinline__ unsigned short f2bf(float f) {
    union { float f; uint32_t u; } v; v.f = f;
    const uint32_t u = v.u;
    return (unsigned short)((u + 0x7fffu + ((u >> 16) & 1u)) >> 16);  // RNE
}
__device__ __forceinline__ float bf2f_lo(uint32_t u) {
    union { uint32_t u; float f; } v; v.u = u << 16; return v.f;
}
__device__ __forceinline__ float bf2f_hi(uint32_t u) {
    union { uint32_t u; float f; } v; v.u = u & 0xffff0000u; return v.f;
}

// ---------------------------------------------------------------------------
// Fused fp32 -> bf16 cast of x (XN), Wv (WN), Wo (WN) in one launch.
// ---------------------------------------------------------------------------
constexpr int XN = Bn * Sn * En;   // 4194304
constexpr int WN = En * En;        // 1048576

__global__ __launch_bounds__(256)
void cast3(const float* __restrict__ x, const float* __restrict__ Wv,
           const float* __restrict__ Wo, unsigned short* __restrict__ xb,
           unsigned short* __restrict__ Wvb, unsigned short* __restrict__ Wob)
{
    const int i = (blockIdx.x * 256 + threadIdx.x) * 4;
    const float* src; unsigned short* dst; int off;
    if (i < XN)           { src = x;  dst = xb;  off = i; }
    else if (i < XN + WN) { src = Wv; dst = Wvb; off = i - XN; }
    else                  { src = Wo; dst = Wob; off = i - XN - WN; }
    const float4 v = *(const float4*)(src + off);
    ushort4 o;
    o.x = f2bf(v.x); o.y = f2bf(v.y); o.z = f2bf(v.z); o.w = f2bf(v.w);
    *(ushort4*)(dst + off) = o;
}

// ---------------------------------------------------------------------------
// bf16 MFMA GEMM (NT): C[m,n] = sum_k A[m,k]*W[n,k] + bias[n].
// Tile 128(M) x 64(N), BK=64, 256 threads = 4 waves in 2x2 over (128,64):
// wave tile 64x32, K-step 64 = 4x2x2 = 16 MFMAs per barrier pair (half the
// barrier-drain count of BK=32). LDS 24 KB -> 2 blocks/CU at grid 512.
// Staging: global_load_lds width=16 into MFMA-fragment-order LDS
// (1024 B chunk = 16 rows x 32 k; lane l -> row (l&15), k (l>>4)*8).
// Compute reads fragments at chunk_base + lane*16 B (conflict-free b128).
// APPLY_MASK zeroes output rows with mask==0; OUT_BF16 stores bf16;
// FUSE_CSUM: each wave owns chunk gc=2*by+wr (64 rows) x 32 cols -> exact
// per-chunk column sums via butterfly shuffle, unique writer into csum.
// ---------------------------------------------------------------------------
template<bool APPLY_MASK, bool OUT_BF16, bool FUSE_CSUM>
__global__ __launch_bounds__(256)
void gemm_mfma(const unsigned short* __restrict__ A, const unsigned short* __restrict__ Bw,
               const float* __restrict__ bias, const int* __restrict__ mask,
               void* __restrict__ Cv, float* __restrict__ csum, int M, int N, int K)
{
    __shared__ __align__(16) unsigned short As[128 * 64];  // 16 KB
    __shared__ __align__(16) unsigned short Bs[64 * 64];   // 8 KB

    const int tid  = threadIdx.x;
    const int lane = tid & 63;
    const int wv   = tid >> 6;      // wave 0..3
    const int wr   = wv >> 1;       // wave row (0..1) -> M
    const int wc   = wv & 1;        // wave col (0..1) -> N
    const int bm   = blockIdx.y * 128;
    const int bn   = blockIdx.x * 64;
    const int m16  = lane & 15;
    const int kq   = lane >> 4;     // k-quarter (staging) / row-quad (C/D)

    f32x4 acc[4][2] = {};

    // Staging addresses. Wave wv: A row-chunks {2wv,2wv+1} x k-chunks {0,1},
    // B row-chunk {wv} x k-chunks {0,1}.
    const int j0 = 2 * wv, j1 = 2 * wv + 1;
    const unsigned short* gA0 = A  + (size_t)(bm + 16 * j0 + m16) * K + kq * 8;
    const unsigned short* gA1 = A  + (size_t)(bm + 16 * j1 + m16) * K + kq * 8;
    const unsigned short* gB0 = Bw + (size_t)(bn + 16 * wv + m16) * K + kq * 8;
    unsigned short* lA00 = &As[(j0 * 2 + 0) * 512];
    unsigned short* lA01 = &As[(j0 * 2 + 1) * 512];
    unsigned short* lA10 = &As[(j1 * 2 + 0) * 512];
    unsigned short* lA11 = &As[(j1 * 2 + 1) * 512];
    unsigned short* lB00 = &Bs[(wv * 2 + 0) * 512];
    unsigned short* lB01 = &Bs[(wv * 2 + 1) * 512];

    for (int k0 = 0; k0 < K; k0 += 64) {
        __syncthreads();   // previous iteration's frag reads done
        __builtin_amdgcn_global_load_lds(GLOBAL_AS(gA0 + k0),      LDS_AS(lA00), 16, 0, 0);
        __builtin_amdgcn_global_load_lds(GLOBAL_AS(gA0 + k0 + 32), LDS_AS(lA01), 16, 0, 0);
        __builtin_amdgcn_global_load_lds(GLOBAL_AS(gA1 + k0),      LDS_AS(lA10), 16, 0, 0);
        __builtin_amdgcn_global_load_lds(GLOBAL_AS(gA1 + k0 + 32), LDS_AS(lA11), 16, 0, 0);
        __builtin_amdgcn_global_load_lds(GLOBAL_AS(gB0 + k0),      LDS_AS(lB00), 16, 0, 0);
        __builtin_amdgcn_global_load_lds(GLOBAL_AS(gB0 + k0 + 32), LDS_AS(lB01), 16, 0, 0);
        __syncthreads();   // implies vmcnt(0): staging landed

        bf16x8 af[4][2], bfr[2][2];
#pragma unroll
        for (int i = 0; i < 4; ++i)
#pragma unroll
            for (int kk = 0; kk < 2; ++kk)
                af[i][kk] = *(const bf16x8*)&As[((wr * 4 + i) * 2 + kk) * 512 + lane * 8];
#pragma unroll
        for (int j = 0; j < 2; ++j)
#pragma unroll
            for (int kk = 0; kk < 2; ++kk)
                bfr[j][kk] = *(const bf16x8*)&Bs[((wc * 2 + j) * 2 + kk) * 512 + lane * 8];
#pragma unroll
        for (int kk = 0; kk < 2; ++kk)
#pragma unroll
            for (int i = 0; i < 4; ++i)
#pragma unroll
                for (int j = 0; j < 2; ++j)
                    acc[i][j] = __builtin_amdgcn_mfma_f32_16x16x32_bf16(af[i][kk], bfr[j][kk], acc[i][j], 0, 0, 0);
    }

    // Epilogue. C/D layout: col = lane&15, row = (lane>>4)*4 + reg.
    float colsum[2] = {0.0f, 0.0f};
#pragma unroll
    for (int i = 0; i < 4; ++i) {
        const int r0 = bm + wr * 64 + i * 16 + kq * 4;
#pragma unroll
        for (int j = 0; j < 2; ++j) {
            const int c0 = bn + wc * 32 + j * 16 + m16;
            const float bcol = bias[c0];
#pragma unroll
            for (int r = 0; r < 4; ++r) {
                const int row = r0 + r;
                float val = acc[i][j][r] + bcol;
                if (APPLY_MASK) val = (mask[row] == 0) ? 0.0f : val;
                if (FUSE_CSUM) colsum[j] += val;
                if (OUT_BF16)
                    ((unsigned short*)Cv)[(size_t)row * N + c0] = f2bf(val);
                else
                    ((float*)Cv)[(size_t)row * N + c0] = val;
            }
        }
    }

    if (FUSE_CSUM) {
        // Wave wr's 64 rows are exactly global chunk gc = 2*by + wr.
        const int gc = 2 * blockIdx.y + wr;
#pragma unroll
        for (int j = 0; j < 2; ++j) {
            float s = colsum[j];
            s += __shfl_xor(s, 16, 64);
            s += __shfl_xor(s, 32, 64);
            if (kq == 0)
                csum[(size_t)gc * En + bn + wc * 32 + j * 16 + m16] = s;
        }
    }
}

// ---------------------------------------------------------------------------
// Exclusive scan over chunk sums per (b,e) + total T.
// ---------------------------------------------------------------------------
__global__ __launch_bounds__(256)
void chunk_scan(const float* __restrict__ csum, float* __restrict__ cscan,
                float* __restrict__ Tbuf)
{
    const int idx = blockIdx.x * 256 + threadIdx.x;   // b*E + e
    float run = 0.0f;
    const int b = idx >> 10;
    const int e = idx & (En - 1);
    for (int c = 0; c < NCH; ++c) {
        const size_t off = ((size_t)b * NCH + c) * En + e;
        const float v = csum[off];
        cscan[off] = run;
        run += v;
    }
    Tbuf[idx] = run;
}

// ---------------------------------------------------------------------------
// Fused within-chunk prefix + weighted combine -> opre (bf16).
// out_pre[b,i,e] = (w2*Pref[i&~1] + (i odd)*w1*vm[i-1] + w0*(T - Pref[i])) / Z
// Z = (i&~1)*w2 + (i odd)*w1 + (S-i)*w0 + 1e-8   (pre-mask normalization)
// 2 columns/thread (same head since e is even and dh=64).
// ---------------------------------------------------------------------------
__global__ __launch_bounds__(256)
void combine(const unsigned short* __restrict__ vm, const float* __restrict__ cscan,
             const float* __restrict__ Tbuf, const float* __restrict__ hier,
             unsigned short* __restrict__ opre)
{
    const int ep = blockIdx.x * 256 + threadIdx.x;
    const int e = ep * 2;
    const int c = blockIdx.y;
    const int b = blockIdx.z;
    const int h = e >> 6;   // dh = 64

    const float w0 = hier[((size_t)b * Hn + h) * 3 + 0];
    const float w1 = hier[((size_t)b * Hn + h) * 3 + 1] * 0.5f;
    const float w2 = hier[((size_t)b * Hn + h) * 3 + 2] * 0.25f;
    const float T0 = Tbuf[(size_t)b * En + e];
    const float T1 = Tbuf[(size_t)b * En + e + 1];

    const size_t co = ((size_t)b * NCH + c) * En + e;
    float run0 = cscan[co], run1 = cscan[co + 1];
    float prev0 = 0.0f, prev1 = 0.0f;
    const size_t base = ((size_t)b * Sn + c * CHUNK) * En + e;

    for (int t = 0; t < CHUNK; ++t) {
        const int i = c * CHUNK + t;
        const uint32_t u = *(const uint32_t*)(vm + base + (size_t)t * En);
        const float cur0 = bf2f_lo(u), cur1 = bf2f_hi(u);
        float num0, num1, Z;
        if (i & 1) {
            num0 = w2 * (run0 - prev0) + w1 * prev0 + w0 * (T0 - run0);
            num1 = w2 * (run1 - prev1) + w1 * prev1 + w0 * (T1 - run1);
            Z = (float)(i - 1) * w2 + w1 + (float)(Sn - i) * w0 + 1e-8f;
        } else {
            num0 = w2 * run0 + w0 * (T0 - run0);
            num1 = w2 * run1 + w0 * (T1 - run1);
            Z = (float)i * w2 + (float)(Sn - i) * w0 + 1e-8f;
        }
        const float rz = 1.0f / Z;
        const uint32_t o = (uint32_t)f2bf(num0 * rz) | ((uint32_t)f2bf(num1 * rz) << 16);
        *(uint32_t*)(opre + base + (size_t)t * En) = o;
        run0 += cur0; run1 += cur1;
        prev0 = cur0; prev1 = cur1;
    }
}

// ---------------------------------------------------------------------------
extern "C" void kernel_launch(void* const* d_in, const int* in_sizes, int n_in,
                              void* d_out, int out_size, void* d_ws, size_t ws_size,
                              hipStream_t stream)
{
    // 0:x 1:attention_mask 2:level_indices 3:Wq 4:bq 5:Wk 6:bk 7:Wv 8:bv 9:hier 10:Wo 11:bo
    const float* x    = (const float*)d_in[0];
    const int*   mask = (const int*)d_in[1];
    const float* Wv   = (const float*)d_in[7];
    const float* bv   = (const float*)d_in[8];
    const float* hier = (const float*)d_in[9];
    const float* Wo   = (const float*)d_in[10];
    const float* bo   = (const float*)d_in[11];
    float* out = (float*)d_out;

    const int M = Bn * Sn, N = En, K = En;

    char* ws = (char*)d_ws;
    unsigned short* xb    = (unsigned short*)ws;  ws += (size_t)M * K * 2;        // 8 MB
    unsigned short* Wvb   = (unsigned short*)ws;  ws += (size_t)N * K * 2;        // 2 MB
    unsigned short* Wob   = (unsigned short*)ws;  ws += (size_t)N * K * 2;        // 2 MB
    unsigned short* vmb   = (unsigned short*)ws;  ws += (size_t)M * N * 2;        // 8 MB
    float*          csum  = (float*)ws;           ws += (size_t)Bn * NCH * En * 4;
    float*          cscan = (float*)ws;           ws += (size_t)Bn * NCH * En * 4;
    float*          Tbuf  = (float*)ws;           ws += (size_t)Bn * En * 4;
    unsigned short* opreb = (unsigned short*)ws;  ws += (size_t)M * N * 2;        // 8 MB

    dim3 threads(256);

    // Fused casts to bf16 (x, Wv, Wo)
    cast3<<<dim3((XN + 2 * WN) / 1024), threads, 0, stream>>>(x, Wv, Wo, xb, Wvb, Wob);

    dim3 gemm_grid(N / 64, M / 128);   // (16, 32) = 512 blocks = 2/CU

    // 1) vm = mask ? (x @ Wv.T + bv) : 0   (bf16 out) + fused per-chunk col sums
    gemm_mfma<true, true, true><<<gemm_grid, threads, 0, stream>>>(xb, Wvb, bv, mask, vmb, csum, M, N, K);
    // 2) exclusive prefix scan of chunk sums along s
    chunk_scan<<<dim3((Bn * En) / 256), threads, 0, stream>>>(csum, cscan, Tbuf);
    // 3) weighted combine -> opre (bf16)
    combine<<<dim3(En / 512, NCH, Bn), threads, 0, stream>>>(vmb, cscan, Tbuf, hier, opreb);
    // 4) out = opre @ Wo.T + bo  (fp32 out)
    gemm_mfma<false, false, false><<<gemm_grid, threads, 0, stream>>>(opreb, Wob, bo, nullptr, out, nullptr, M, N, K);
}